// Round 4
// baseline (298.937 us; speedup 1.0000x reference)
//
#include <hip/hip_runtime.h>

#define SQ3F 0.35355339059327379f

__device__ __forceinline__ float rfl(float v) {
    return __int_as_float(__builtin_amdgcn_readfirstlane(__float_as_int(v)));
}

// Forward 2x2x2 Haar butterfly. v index = z*4+y*2+x. o index = fz*4+fy*2+fx.
__device__ __forceinline__ void haar_fwd(const float v[8], float o[8]) {
    float ax[8];
#pragma unroll
    for (int i = 0; i < 4; ++i) {
        float a = v[2 * i], b = v[2 * i + 1];
        ax[2 * i]     = a + b;
        ax[2 * i + 1] = b - a;
    }
    float ay[8];
#pragma unroll
    for (int z = 0; z < 2; ++z)
#pragma unroll
        for (int bx = 0; bx < 2; ++bx) {
            float a = ax[z * 4 + bx], b = ax[z * 4 + 2 + bx];
            ay[z * 4 + bx]     = a + b;
            ay[z * 4 + 2 + bx] = b - a;
        }
#pragma unroll
    for (int j = 0; j < 4; ++j) {
        float a = ay[j], b = ay[4 + j];
        o[j]     = (a + b) * SQ3F;
        o[4 + j] = (b - a) * SQ3F;
    }
}

// Inverse Haar. t index = fz*4+fy*2+fx. o index = z*4+y*2+x.
__device__ __forceinline__ void haar_inv(const float t[8], float o[8]) {
    float az[8];
#pragma unroll
    for (int j = 0; j < 4; ++j) {
        float lo = t[j], hi = t[4 + j];
        az[j]     = lo + hi;
        az[4 + j] = lo - hi;
    }
    float ay[8];
#pragma unroll
    for (int z = 0; z < 2; ++z)
#pragma unroll
        for (int bx = 0; bx < 2; ++bx) {
            float lo = az[z * 4 + bx], hi = az[z * 4 + 2 + bx];
            ay[z * 4 + bx]     = lo + hi;
            ay[z * 4 + 2 + bx] = lo - hi;
        }
#pragma unroll
    for (int i = 0; i < 4; ++i) {
        float lo = ay[2 * i], hi = ay[2 * i + 1];
        o[2 * i]     = (lo + hi) * SQ3F;
        o[2 * i + 1] = (lo - hi) * SQ3F;
    }
}

// ============ Fused level-0: DWT + depthwise conv + soft-threshold =========
// (R2 version restored exactly — best measured. R3's register-prefetch
// restructure regressed: compiler sank the unpinned loads, and float2
// staging doubled VMEM issue.)
__global__ __launch_bounds__(512, 4) void fused_l0_k(
    const float* __restrict__ x, const float* __restrict__ wt,
    const float* __restrict__ wscale, const float* __restrict__ lambd_p,
    float* __restrict__ t0, float* __restrict__ ll) {
    __shared__ __align__(16) float pl[8][32][36];
    int bx   = blockIdx.x;
    int slab = bx & 7;
    int c    = bx >> 3;
    int z0   = slab * 4;
    int tid  = threadIdx.x;

    // zero the x-pad columns once (512 pad slots, one per thread)
    {
        int fi   = tid >> 6;
        int rowi = (tid >> 1) & 31;
        pl[fi][rowi][(tid & 1) * 33] = 0.f;
    }

    int f    = __builtin_amdgcn_readfirstlane(tid >> 6);  // band, wave-uniform
    int lane = tid & 63;
    int cty  = lane >> 1;         // conv row 0..31
    int cx0i = (lane & 1) * 16;   // 16-wide x chunk
    int cc   = c * 8 + f;
    float wv[27];
    const float* wp = wt + cc * 27;
#pragma unroll
    for (int k = 0; k < 27; ++k) wv[k] = wp[k];
    float lam = *lambd_p;
    float sc  = wscale[cc];

    const float* xc = x + ((long)c << 18);

    float acc[3][16];
#pragma unroll
    for (int s = 0; s < 3; ++s)
#pragma unroll
        for (int j = 0; j < 16; ++j) acc[s][j] = 0.f;

    // pp fully unrolled so acc/ring indices are compile-time constants.
#pragma unroll
    for (int pp = 0; pp < 6; ++pp) {
        int p       = z0 - 1 + pp;
        bool pvalid = (p >= 0) && (p <= 31);  // wave-uniform
        __syncthreads();
        if (pvalid) {
            // DWT plane p -> LDS (1024 cells, 2 x-adjacent cells per thread;
            // global reads are float4 = both cells' x-pairs in one load)
            int cell = 2 * tid;
            int y    = cell >> 5;
            int xx   = cell & 31;  // even
            float v0[8], v1[8];
#pragma unroll
            for (int z = 0; z < 2; ++z)
#pragma unroll
                for (int yy = 0; yy < 2; ++yy) {
                    float4 q = *(const float4*)(xc + (((2 * p + z) << 6) +
                                                      (2 * y + yy)) * 64 + 2 * xx);
                    v0[z * 4 + yy * 2]     = q.x;
                    v0[z * 4 + yy * 2 + 1] = q.y;
                    v1[z * 4 + yy * 2]     = q.z;
                    v1[z * 4 + yy * 2 + 1] = q.w;
                }
            float o0[8], o1[8];
            haar_fwd(v0, o0);
            haar_fwd(v1, o1);
#pragma unroll
            for (int k = 0; k < 8; ++k) {
                pl[k][y][xx + 1] = o0[k];
                pl[k][y][xx + 2] = o1[k];
            }
            if (pp >= 1 && pp <= 4)  // interior plane: owns ll write
                *(float2*)(ll + (c << 15) + (p << 10) + cell) =
                    float2{o0[0], o1[0]};
        }
        __syncthreads();
        if (pvalid) {
            // fold plane p into pending outputs zc = p+1-dz (rel = pp-dz)
#pragma unroll
            for (int dy = 0; dy < 3; ++dy) {
                int yy = cty - 1 + dy;
                if ((unsigned)yy < 32u) {
                    float r[18];
                    {
                        const float* rp = &pl[f][yy][cx0i];
                        float4 a0 = *(const float4*)(rp);
                        float4 a1 = *(const float4*)(rp + 4);
                        float4 a2 = *(const float4*)(rp + 8);
                        float4 a3 = *(const float4*)(rp + 12);
                        float2 a4 = *(const float2*)(rp + 16);
                        r[0]  = a0.x; r[1]  = a0.y; r[2]  = a0.z; r[3]  = a0.w;
                        r[4]  = a1.x; r[5]  = a1.y; r[6]  = a1.z; r[7]  = a1.w;
                        r[8]  = a2.x; r[9]  = a2.y; r[10] = a2.z; r[11] = a2.w;
                        r[12] = a3.x; r[13] = a3.y; r[14] = a3.z; r[15] = a3.w;
                        r[16] = a4.x; r[17] = a4.y;
                    }
#pragma unroll
                    for (int dz = 0; dz < 3; ++dz) {
                        int rel = pp - dz;
                        if (rel >= 0 && rel <= 3) {  // compile-time
                            int s = rel % 3;         // compile-time
#pragma unroll
                            for (int dx = 0; dx < 3; ++dx) {
                                float wgt = wv[dz * 9 + dy * 3 + dx];
#pragma unroll
                                for (int j = 0; j < 16; ++j)
                                    acc[s][j] += r[dx + j] * wgt;
                            }
                        }
                    }
                }
            }
        }
        // finalize output zc = p-1 (rel = pp-2) — needs planes p-2..p done
        {
            int rel = pp - 2;
            if (rel >= 0 && rel <= 3) {  // compile-time
                int zc = z0 + rel;
                int s  = rel % 3;  // compile-time
                float res[16];
#pragma unroll
                for (int j = 0; j < 16; ++j) {
                    float t = acc[s][j];
                    if (f != 0) {
                        float a = fabsf(t) - lam;
                        t       = a > 0.f ? copysignf(a, t) : 0.f;
                    }
                    res[j]    = t * sc;
                    acc[s][j] = 0.f;
                }
                float* op = t0 + ((long)cc << 15) + (zc << 10) + cty * 32 + cx0i;
#pragma unroll
                for (int q = 0; q < 4; ++q)
                    *(float4*)(op + q * 4) = float4{res[q * 4], res[q * 4 + 1],
                                                    res[q * 4 + 2], res[q * 4 + 3]};
            }
        }
    }
}

// ===================== Level-1 kernels =======================
template <int SO>
__global__ __launch_bounds__(256) void dwt3_k(const float* __restrict__ in,
                                              int inChStride,
                                              float* __restrict__ out) {
    constexpr int SI = SO * 2;
    int idx = blockIdx.x * 256 + threadIdx.x;
    int w = idx % SO;
    int h = (idx / SO) % SO;
    int d = (idx / (SO * SO)) % SO;
    int c = idx / (SO * SO * SO);
    const float* ip = in + (long)c * inChStride;
    float v[8];
#pragma unroll
    for (int z = 0; z < 2; ++z)
#pragma unroll
        for (int y = 0; y < 2; ++y) {
            const float2 p =
                *(const float2*)(ip + ((2 * d + z) * SI + (2 * h + y)) * SI + 2 * w);
            v[z * 4 + y * 2]     = p.x;
            v[z * 4 + y * 2 + 1] = p.y;
        }
    float o[8];
    haar_fwd(v, o);
    int s = (d * SO + h) * SO + w;
#pragma unroll
    for (int f = 0; f < 8; ++f) out[(c * 8 + f) * (SO * SO * SO) + s] = o[f];
}

template <int S, int PH>
__device__ __forceinline__ void conv_step(const float* __restrict__ ip, int zo,
                                          int ty, int x0,
                                          const float* __restrict__ wv,
                                          float win[3][3][6], float lam, float sc,
                                          bool hf, float* __restrict__ op) {
    constexpr int sPrev = (PH + 2) % 3;
    constexpr int sCur  = PH;
    constexpr int sNext = (PH + 1) % 3;
    {
        int zz = zo + 1;
        bool zok = zz < S;
        const float* pp = ip + zz * S * S;
#pragma unroll
        for (int dy = 0; dy < 3; ++dy) {
            int yy  = ty - 1 + dy;
            bool yok = zok && ((unsigned)yy < (unsigned)S);
            const float* rp = pp + yy * S;
            win[sNext][dy][0] = (yok && x0 > 0) ? rp[x0 - 1] : 0.f;
            float4 m = yok ? *(const float4*)(rp + x0) : float4{0.f, 0.f, 0.f, 0.f};
            win[sNext][dy][1] = m.x;
            win[sNext][dy][2] = m.y;
            win[sNext][dy][3] = m.z;
            win[sNext][dy][4] = m.w;
            win[sNext][dy][5] = (yok && (x0 + 4 < S)) ? rp[x0 + 4] : 0.f;
        }
    }
    float acc[4] = {0.f, 0.f, 0.f, 0.f};
#pragma unroll
    for (int dz = 0; dz < 3; ++dz) {
        const float(*wp)[6] = (dz == 0) ? win[sPrev] : (dz == 1) ? win[sCur] : win[sNext];
#pragma unroll
        for (int dy = 0; dy < 3; ++dy)
#pragma unroll
            for (int dx = 0; dx < 3; ++dx) {
                float wgt = wv[dz * 9 + dy * 3 + dx];
#pragma unroll
                for (int j = 0; j < 4; ++j) acc[j] += wp[dy][dx + j] * wgt;
            }
    }
    float4 r;
    float* rr = (float*)&r;
#pragma unroll
    for (int j = 0; j < 4; ++j) {
        float t = acc[j];
        if (hf) {
            float a = fabsf(t) - lam;
            t       = a > 0.f ? copysignf(a, t) : 0.f;
        }
        rr[j] = t * sc;
    }
    *(float4*)(op + (zo * S + ty) * S + x0) = r;
}

// load plane z into win[SLOT] (zeros if z out of range)
template <int S, int SLOT>
__device__ __forceinline__ void load_win_plane(const float* __restrict__ ip,
                                               int z, int ty, int x0,
                                               float win[3][3][6]) {
    bool zok = ((unsigned)z < (unsigned)S);
    const float* pp = ip + z * S * S;
#pragma unroll
    for (int dy = 0; dy < 3; ++dy) {
        int yy  = ty - 1 + dy;
        bool yok = zok && ((unsigned)yy < (unsigned)S);
        const float* rp = pp + yy * S;
        win[SLOT][dy][0] = (yok && x0 > 0) ? rp[x0 - 1] : 0.f;
        float4 m = yok ? *(const float4*)(rp + x0) : float4{0.f, 0.f, 0.f, 0.f};
        win[SLOT][dy][1] = m.x;
        win[SLOT][dy][2] = m.y;
        win[SLOT][dy][3] = m.z;
        win[SLOT][dy][4] = m.w;
        win[SLOT][dy][5] = (yok && (x0 + 4 < S)) ? rp[x0 + 4] : 0.f;
    }
}

// 4-z-step chunk starting at z0; buffer slot of plane q is q%3, PH0 = z0%3.
template <int S, int PH0>
__device__ __forceinline__ void run_chunk(const float* __restrict__ ip, int z0,
                                          int ty, int x0,
                                          const float* __restrict__ wv,
                                          float win[3][3][6], float lam, float sc,
                                          bool hf, float* __restrict__ op) {
    load_win_plane<S, (PH0 + 2) % 3>(ip, z0 - 1, ty, x0, win);
    load_win_plane<S, PH0>(ip, z0, ty, x0, win);
    conv_step<S, PH0>(ip, z0, ty, x0, wv, win, lam, sc, hf, op);
    conv_step<S, (PH0 + 1) % 3>(ip, z0 + 1, ty, x0, wv, win, lam, sc, hf, op);
    conv_step<S, (PH0 + 2) % 3>(ip, z0 + 2, ty, x0, wv, win, lam, sc, hf, op);
    conv_step<S, PH0>(ip, z0 + 3, ty, x0, wv, win, lam, sc, hf, op);
}

// z split into 4 chunks of 4 -> grid 512 blocks.
template <int S, int CPB>
__global__ __launch_bounds__(256) void dwconv_soft_chunk_k(
    const float* __restrict__ in, const float* __restrict__ wt,
    const float* __restrict__ wscale, const float* __restrict__ lambd_p,
    float* __restrict__ out) {
    constexpr int TX = S / 4;
    int tid = threadIdx.x;
    int tx  = tid % TX;
    int ty  = (tid / TX) % S;
    int cs  = tid / (TX * S);
    int zc  = blockIdx.x & 3;
    int cg  = blockIdx.x >> 2;
    int cc  = cg * CPB + cs;
    const float* ip = in + (long)cc * (S * S * S);
    float* op       = out + (long)cc * (S * S * S);
    float wv[27];
#pragma unroll
    for (int k = 0; k < 27; ++k) wv[k] = wt[cc * 27 + k];
    float lam = *lambd_p;
    float sc  = wscale[cc];
    bool hf   = (cc & 7) != 0;
    int x0    = 4 * tx;

    float win[3][3][6];
    switch (zc) {
        case 0:  run_chunk<S, 0>(ip, 0,  ty, x0, wv, win, lam, sc, hf, op); break;
        case 1:  run_chunk<S, 1>(ip, 4,  ty, x0, wv, win, lam, sc, hf, op); break;
        case 2:  run_chunk<S, 2>(ip, 8,  ty, x0, wv, win, lam, sc, hf, op); break;
        default: run_chunk<S, 0>(ip, 12, ty, x0, wv, win, lam, sc, hf, op); break;
    }
}

// ========== Final: LDS-tiled base conv + level-1 idwt + level-0 idwt =======
// R4: SAME 16z x 8y x 64x tile as final_k2 (traffic-identical: R1 proved the
// tile must not shrink) but 512 threads/block, half the per-thread work.
// Resident waves/CU: 12 -> 24 (3 blocks x 8 waves; LDS 48.2KB -> 3 blocks/CU).
// Conv weights + bias/scale hoisted to SGPRs (wave-uniform) to fit the
// 85-VGPR cap of __launch_bounds__(512,6).
// Thread: 2 w-cells (4 x outputs), epilogue identical to R1's final_k3
// (harness-verified) with this tile.
__global__ __launch_bounds__(512, 6) void final_k2w(
    const float* __restrict__ x, const float* __restrict__ t0,
    const float* __restrict__ t1, const float* __restrict__ bw,
    const float* __restrict__ bb, const float* __restrict__ bscale,
    float* __restrict__ out) {
    __shared__ float xs[18 * 10 * 67];
    int bx = blockIdx.x;
    int c  = bx >> 5;
    int ti = bx & 31;
    int dt = ti >> 3;  // z tile (16 thick)
    int ht = ti & 7;   // y tile (8 thick)
    const float* xc = x + ((long)c << 18);
    int zg0 = 16 * dt - 1, yg0 = 8 * ht - 1;
    for (int i = threadIdx.x; i < 18 * 10 * 66; i += 512) {
        int pz = i / 660;
        int r  = i - pz * 660;
        int py = r / 66;
        int px = r - py * 66;
        int zg = zg0 + pz, yg = yg0 + py, xg = px - 1;
        bool ok = ((unsigned)zg < 64u) && ((unsigned)yg < 64u) && ((unsigned)xg < 64u);
        xs[(pz * 10 + py) * 67 + px] = ok ? xc[(zg << 12) + (yg << 6) + xg] : 0.f;
    }
    const float* wp0 = bw + c * 27;
    float wv[27];
#pragma unroll
    for (int k = 0; k < 27; ++k) wv[k] = rfl(wp0[k]);   // SGPRs
    float bias = rfl(bb[c]), scl = rfl(bscale[c]);      // SGPRs
    __syncthreads();

    int tid = threadIdx.x;
    int wc  = tid & 15;        // owns w-cells 2wc,2wc+1 -> x outputs 4wc..4wc+3
    int hc  = (tid >> 4) & 3;  // h cell in tile
    int dc  = tid >> 6;        // d cell in tile
    int d   = dt * 8 + dc;
    int h   = ht * 4 + hc;
    int x0  = wc * 4;          // output x base

    float acc[2][2][4];
#pragma unroll
    for (int oz = 0; oz < 2; ++oz)
#pragma unroll
        for (int oy = 0; oy < 2; ++oy)
#pragma unroll
            for (int m = 0; m < 4; ++m) acc[oz][oy][m] = 0.f;

#pragma unroll
    for (int pz = 0; pz < 4; ++pz) {
        float r[4][6];
#pragma unroll
        for (int py = 0; py < 4; ++py)
#pragma unroll
            for (int k = 0; k < 6; ++k)
                r[py][k] = xs[((2 * dc + pz) * 10 + (2 * hc + py)) * 67 + 4 * wc + k];
#pragma unroll
        for (int oz = 0; oz < 2; ++oz) {
            int kz = pz - oz;
            if (kz >= 0 && kz <= 2) {  // compile-time
#pragma unroll
                for (int py = 0; py < 4; ++py)
#pragma unroll
                    for (int oy = 0; oy < 2; ++oy) {
                        int ky = py - oy;
                        if (ky >= 0 && ky <= 2) {  // compile-time
#pragma unroll
                            for (int kx = 0; kx < 3; ++kx) {
                                float wgt = wv[kz * 9 + ky * 3 + kx];
#pragma unroll
                                for (int m = 0; m < 4; ++m)
                                    acc[oz][oy][m] += r[py][m + kx] * wgt;
                            }
                        }
                    }
            }
        }
    }

    // epilogue: t0 (float2/band) + t1 idwt into band0, haar_inv, store float4
    int cell0 = (d << 10) + (h << 5) + 2 * wc;
    float2 t0v[8];
#pragma unroll
    for (int f = 0; f < 8; ++f)
        t0v[f] = *(const float2*)(t0 + (((long)(c * 8 + f)) << 15) + cell0);
    int s1b = ((d >> 1) * 16 + (h >> 1)) * 16 + wc;  // parent w-cell = wc
    float t1v[8];
#pragma unroll
    for (int f = 0; f < 8; ++f)
        t1v[f] = t1[((c * 8 + f) << 12) + s1b];

    float c0[8], c1[8];
#pragma unroll
    for (int j = 0; j < 2; ++j) {  // w-cell 2wc+j
        float tf[8];
#pragma unroll
        for (int f = 0; f < 8; ++f) tf[f] = j ? t0v[f].y : t0v[f].x;
        float add = 0.f;
#pragma unroll
        for (int f = 0; f < 8; ++f) {
            float sg = 1.f;
            if ((f & 4) && (d & 1)) sg = -sg;
            if ((f & 2) && (h & 1)) sg = -sg;
            if ((f & 1) && j) sg = -sg;
            add += sg * t1v[f];
        }
        tf[0] += add * SQ3F;
        haar_inv(tf, j ? c1 : c0);
    }

#pragma unroll
    for (int oz = 0; oz < 2; ++oz)
#pragma unroll
        for (int oy = 0; oy < 2; ++oy) {
            float4 rv;
            rv.x = (acc[oz][oy][0] + bias) * scl + c0[oz * 4 + oy * 2];
            rv.y = (acc[oz][oy][1] + bias) * scl + c0[oz * 4 + oy * 2 + 1];
            rv.z = (acc[oz][oy][2] + bias) * scl + c1[oz * 4 + oy * 2];
            rv.w = (acc[oz][oy][3] + bias) * scl + c1[oz * 4 + oy * 2 + 1];
            *(float4*)(out + ((long)c << 18) + ((2 * d + oz) << 12) +
                       ((2 * h + oy) << 6) + x0) = rv;
        }
}

extern "C" void kernel_launch(void* const* d_in, const int* in_sizes, int n_in,
                              void* d_out, int out_size, void* d_ws, size_t ws_size,
                              hipStream_t stream) {
    const float* x      = (const float*)d_in[0];
    const float* base_w = (const float*)d_in[1];
    const float* base_b = (const float*)d_in[2];
    const float* base_s = (const float*)d_in[3];
    const float* w0     = (const float*)d_in[4];
    const float* w1     = (const float*)d_in[5];
    const float* ws0    = (const float*)d_in[6];
    const float* ws1    = (const float*)d_in[7];
    const float* lambd  = (const float*)d_in[8];
    float* out = (float*)d_out;

    // Workspace (floats): ll 2.1M | t0 16.8M | cx1 2.1M | t1 2.1M
    float* ll  = (float*)d_ws;
    float* t0  = ll + 2097152;
    float* cx1 = t0 + 16777216;
    float* t1  = cx1 + 2097152;

    // Level 0 fused: x -> t0 (conv+soft+scale, all 8 bands) + raw LL
    fused_l0_k<<<512, 512, 0, stream>>>(x, w0, ws0, lambd, t0, ll);
    // Level 1
    dwt3_k<16><<<1024, 256, 0, stream>>>(ll, 32768, cx1);
    dwconv_soft_chunk_k<16, 4><<<512, 256, 0, stream>>>(cx1, w1, ws1, lambd, t1);
    // Final: base conv + level-1 idwt (fused) + level-0 idwt
    final_k2w<<<2048, 512, 0, stream>>>(x, t0, t1, base_w, base_b, base_s, out);
}

// Round 5
// 251.380 us; speedup vs baseline: 1.1892x; 1.1892x over previous
//
#include <hip/hip_runtime.h>

#define SQ3F 0.35355339059327379f

__device__ __forceinline__ float rfl(float v) {
    return __int_as_float(__builtin_amdgcn_readfirstlane(__float_as_int(v)));
}

// Forward 2x2x2 Haar butterfly. v index = z*4+y*2+x. o index = fz*4+fy*2+fx.
__device__ __forceinline__ void haar_fwd(const float v[8], float o[8]) {
    float ax[8];
#pragma unroll
    for (int i = 0; i < 4; ++i) {
        float a = v[2 * i], b = v[2 * i + 1];
        ax[2 * i]     = a + b;
        ax[2 * i + 1] = b - a;
    }
    float ay[8];
#pragma unroll
    for (int z = 0; z < 2; ++z)
#pragma unroll
        for (int bx = 0; bx < 2; ++bx) {
            float a = ax[z * 4 + bx], b = ax[z * 4 + 2 + bx];
            ay[z * 4 + bx]     = a + b;
            ay[z * 4 + 2 + bx] = b - a;
        }
#pragma unroll
    for (int j = 0; j < 4; ++j) {
        float a = ay[j], b = ay[4 + j];
        o[j]     = (a + b) * SQ3F;
        o[4 + j] = (b - a) * SQ3F;
    }
}

// Inverse Haar. t index = fz*4+fy*2+fx. o index = z*4+y*2+x.
__device__ __forceinline__ void haar_inv(const float t[8], float o[8]) {
    float az[8];
#pragma unroll
    for (int j = 0; j < 4; ++j) {
        float lo = t[j], hi = t[4 + j];
        az[j]     = lo + hi;
        az[4 + j] = lo - hi;
    }
    float ay[8];
#pragma unroll
    for (int z = 0; z < 2; ++z)
#pragma unroll
        for (int bx = 0; bx < 2; ++bx) {
            float lo = az[z * 4 + bx], hi = az[z * 4 + 2 + bx];
            ay[z * 4 + bx]     = lo + hi;
            ay[z * 4 + 2 + bx] = lo - hi;
        }
#pragma unroll
    for (int i = 0; i < 4; ++i) {
        float lo = ay[2 * i], hi = ay[2 * i + 1];
        o[2 * i]     = (lo + hi) * SQ3F;
        o[2 * i + 1] = (lo - hi) * SQ3F;
    }
}

// ============ Fused level-0: DWT + depthwise conv + soft-threshold =========
// R5: same staging/fold inner code as the validated R2 version, but
//  - 16 slabs x 2 z-cells (was 8 x 4): grid 1024 (4 blocks/CU by LDS),
//    serial chain 4 phases (was 6), acc ring 3->2 slots (-16 VGPR).
//  - conv weights + scale + lambda in SGPRs via readfirstlane (band is
//    wave-uniform): -29 VGPR. Target <=85 VGPR -> 24 waves/CU.
// Traffic: z-halo amplification 1.25->1.5x (+~36MB) but all 1024 blocks
// co-resident => adjacent slabs' shared halo planes L2/L3-absorb.
__global__ __launch_bounds__(512, 6) void fused_l0_k(
    const float* __restrict__ x, const float* __restrict__ wt,
    const float* __restrict__ wscale, const float* __restrict__ lambd_p,
    float* __restrict__ t0, float* __restrict__ ll) {
    __shared__ __align__(16) float pl[8][32][36];
    int bx   = blockIdx.x;
    int slab = bx & 15;
    int c    = bx >> 4;
    int z0   = slab * 2;
    int tid  = threadIdx.x;

    // zero the x-pad columns once (512 pad slots, one per thread)
    {
        int fi   = tid >> 6;
        int rowi = (tid >> 1) & 31;
        pl[fi][rowi][(tid & 1) * 33] = 0.f;
    }

    int f    = __builtin_amdgcn_readfirstlane(tid >> 6);  // band, wave-uniform
    int lane = tid & 63;
    int cty  = lane >> 1;         // conv row 0..31
    int cx0i = (lane & 1) * 16;   // 16-wide x chunk
    int cc   = c * 8 + f;         // wave-uniform
    float wv[27];
    const float* wp = wt + cc * 27;
#pragma unroll
    for (int k = 0; k < 27; ++k) wv[k] = rfl(wp[k]);  // SGPRs
    float lam = rfl(*lambd_p);
    float sc  = rfl(wscale[cc]);

    const float* xc = x + ((long)c << 18);

    float acc[2][16];
#pragma unroll
    for (int s = 0; s < 2; ++s)
#pragma unroll
        for (int j = 0; j < 16; ++j) acc[s][j] = 0.f;

    // pp fully unrolled so acc/ring indices are compile-time constants.
#pragma unroll
    for (int pp = 0; pp < 4; ++pp) {
        int p       = z0 - 1 + pp;
        bool pvalid = (p >= 0) && (p <= 31);  // wave-uniform
        __syncthreads();
        if (pvalid) {
            // DWT plane p -> LDS (1024 cells, 2 x-adjacent cells per thread;
            // global reads are float4 = both cells' x-pairs in one load)
            int cell = 2 * tid;
            int y    = cell >> 5;
            int xx   = cell & 31;  // even
            float v0[8], v1[8];
#pragma unroll
            for (int z = 0; z < 2; ++z)
#pragma unroll
                for (int yy = 0; yy < 2; ++yy) {
                    float4 q = *(const float4*)(xc + (((2 * p + z) << 6) +
                                                      (2 * y + yy)) * 64 + 2 * xx);
                    v0[z * 4 + yy * 2]     = q.x;
                    v0[z * 4 + yy * 2 + 1] = q.y;
                    v1[z * 4 + yy * 2]     = q.z;
                    v1[z * 4 + yy * 2 + 1] = q.w;
                }
            float o0[8], o1[8];
            haar_fwd(v0, o0);
            haar_fwd(v1, o1);
#pragma unroll
            for (int k = 0; k < 8; ++k) {
                pl[k][y][xx + 1] = o0[k];
                pl[k][y][xx + 2] = o1[k];
            }
            if (pp == 1 || pp == 2)  // interior plane: owns ll write
                *(float2*)(ll + (c << 15) + (p << 10) + cell) =
                    float2{o0[0], o1[0]};
        }
        __syncthreads();
        if (pvalid) {
            // fold plane p into pending outputs zc = p+1-dz (rel = pp-dz)
#pragma unroll
            for (int dy = 0; dy < 3; ++dy) {
                int yy = cty - 1 + dy;
                if ((unsigned)yy < 32u) {
                    float r[18];
                    {
                        const float* rp = &pl[f][yy][cx0i];
                        float4 a0 = *(const float4*)(rp);
                        float4 a1 = *(const float4*)(rp + 4);
                        float4 a2 = *(const float4*)(rp + 8);
                        float4 a3 = *(const float4*)(rp + 12);
                        float2 a4 = *(const float2*)(rp + 16);
                        r[0]  = a0.x; r[1]  = a0.y; r[2]  = a0.z; r[3]  = a0.w;
                        r[4]  = a1.x; r[5]  = a1.y; r[6]  = a1.z; r[7]  = a1.w;
                        r[8]  = a2.x; r[9]  = a2.y; r[10] = a2.z; r[11] = a2.w;
                        r[12] = a3.x; r[13] = a3.y; r[14] = a3.z; r[15] = a3.w;
                        r[16] = a4.x; r[17] = a4.y;
                    }
#pragma unroll
                    for (int dz = 0; dz < 3; ++dz) {
                        int rel = pp - dz;
                        if (rel >= 0 && rel <= 1) {  // compile-time
#pragma unroll
                            for (int dx = 0; dx < 3; ++dx) {
                                float wgt = wv[dz * 9 + dy * 3 + dx];
#pragma unroll
                                for (int j = 0; j < 16; ++j)
                                    acc[rel][j] += r[dx + j] * wgt;
                            }
                        }
                    }
                }
            }
        }
        // finalize output zc = z0+rel (rel = pp-2) — needs planes zc-1..zc+1
        {
            int rel = pp - 2;
            if (rel >= 0 && rel <= 1) {  // compile-time
                int zc = z0 + rel;
                // for slab 15, zc=31 finalizes at pp=3 even though p=32 skipped
                float res[16];
#pragma unroll
                for (int j = 0; j < 16; ++j) {
                    float t = acc[rel][j];
                    if (f != 0) {
                        float a = fabsf(t) - lam;
                        t       = a > 0.f ? copysignf(a, t) : 0.f;
                    }
                    res[j]      = t * sc;
                    acc[rel][j] = 0.f;
                }
                float* op = t0 + ((long)cc << 15) + (zc << 10) + cty * 32 + cx0i;
#pragma unroll
                for (int q = 0; q < 4; ++q)
                    *(float4*)(op + q * 4) = float4{res[q * 4], res[q * 4 + 1],
                                                    res[q * 4 + 2], res[q * 4 + 3]};
            }
        }
    }
}

// ===================== Level-1 kernels =======================
template <int SO>
__global__ __launch_bounds__(256) void dwt3_k(const float* __restrict__ in,
                                              int inChStride,
                                              float* __restrict__ out) {
    constexpr int SI = SO * 2;
    int idx = blockIdx.x * 256 + threadIdx.x;
    int w = idx % SO;
    int h = (idx / SO) % SO;
    int d = (idx / (SO * SO)) % SO;
    int c = idx / (SO * SO * SO);
    const float* ip = in + (long)c * inChStride;
    float v[8];
#pragma unroll
    for (int z = 0; z < 2; ++z)
#pragma unroll
        for (int y = 0; y < 2; ++y) {
            const float2 p =
                *(const float2*)(ip + ((2 * d + z) * SI + (2 * h + y)) * SI + 2 * w);
            v[z * 4 + y * 2]     = p.x;
            v[z * 4 + y * 2 + 1] = p.y;
        }
    float o[8];
    haar_fwd(v, o);
    int s = (d * SO + h) * SO + w;
#pragma unroll
    for (int f = 0; f < 8; ++f) out[(c * 8 + f) * (SO * SO * SO) + s] = o[f];
}

template <int S, int PH>
__device__ __forceinline__ void conv_step(const float* __restrict__ ip, int zo,
                                          int ty, int x0,
                                          const float* __restrict__ wv,
                                          float win[3][3][6], float lam, float sc,
                                          bool hf, float* __restrict__ op) {
    constexpr int sPrev = (PH + 2) % 3;
    constexpr int sCur  = PH;
    constexpr int sNext = (PH + 1) % 3;
    {
        int zz = zo + 1;
        bool zok = zz < S;
        const float* pp = ip + zz * S * S;
#pragma unroll
        for (int dy = 0; dy < 3; ++dy) {
            int yy  = ty - 1 + dy;
            bool yok = zok && ((unsigned)yy < (unsigned)S);
            const float* rp = pp + yy * S;
            win[sNext][dy][0] = (yok && x0 > 0) ? rp[x0 - 1] : 0.f;
            float4 m = yok ? *(const float4*)(rp + x0) : float4{0.f, 0.f, 0.f, 0.f};
            win[sNext][dy][1] = m.x;
            win[sNext][dy][2] = m.y;
            win[sNext][dy][3] = m.z;
            win[sNext][dy][4] = m.w;
            win[sNext][dy][5] = (yok && (x0 + 4 < S)) ? rp[x0 + 4] : 0.f;
        }
    }
    float acc[4] = {0.f, 0.f, 0.f, 0.f};
#pragma unroll
    for (int dz = 0; dz < 3; ++dz) {
        const float(*wp)[6] = (dz == 0) ? win[sPrev] : (dz == 1) ? win[sCur] : win[sNext];
#pragma unroll
        for (int dy = 0; dy < 3; ++dy)
#pragma unroll
            for (int dx = 0; dx < 3; ++dx) {
                float wgt = wv[dz * 9 + dy * 3 + dx];
#pragma unroll
                for (int j = 0; j < 4; ++j) acc[j] += wp[dy][dx + j] * wgt;
            }
    }
    float4 r;
    float* rr = (float*)&r;
#pragma unroll
    for (int j = 0; j < 4; ++j) {
        float t = acc[j];
        if (hf) {
            float a = fabsf(t) - lam;
            t       = a > 0.f ? copysignf(a, t) : 0.f;
        }
        rr[j] = t * sc;
    }
    *(float4*)(op + (zo * S + ty) * S + x0) = r;
}

// load plane z into win[SLOT] (zeros if z out of range)
template <int S, int SLOT>
__device__ __forceinline__ void load_win_plane(const float* __restrict__ ip,
                                               int z, int ty, int x0,
                                               float win[3][3][6]) {
    bool zok = ((unsigned)z < (unsigned)S);
    const float* pp = ip + z * S * S;
#pragma unroll
    for (int dy = 0; dy < 3; ++dy) {
        int yy  = ty - 1 + dy;
        bool yok = zok && ((unsigned)yy < (unsigned)S);
        const float* rp = pp + yy * S;
        win[SLOT][dy][0] = (yok && x0 > 0) ? rp[x0 - 1] : 0.f;
        float4 m = yok ? *(const float4*)(rp + x0) : float4{0.f, 0.f, 0.f, 0.f};
        win[SLOT][dy][1] = m.x;
        win[SLOT][dy][2] = m.y;
        win[SLOT][dy][3] = m.z;
        win[SLOT][dy][4] = m.w;
        win[SLOT][dy][5] = (yok && (x0 + 4 < S)) ? rp[x0 + 4] : 0.f;
    }
}

// 4-z-step chunk starting at z0; buffer slot of plane q is q%3, PH0 = z0%3.
template <int S, int PH0>
__device__ __forceinline__ void run_chunk(const float* __restrict__ ip, int z0,
                                          int ty, int x0,
                                          const float* __restrict__ wv,
                                          float win[3][3][6], float lam, float sc,
                                          bool hf, float* __restrict__ op) {
    load_win_plane<S, (PH0 + 2) % 3>(ip, z0 - 1, ty, x0, win);
    load_win_plane<S, PH0>(ip, z0, ty, x0, win);
    conv_step<S, PH0>(ip, z0, ty, x0, wv, win, lam, sc, hf, op);
    conv_step<S, (PH0 + 1) % 3>(ip, z0 + 1, ty, x0, wv, win, lam, sc, hf, op);
    conv_step<S, (PH0 + 2) % 3>(ip, z0 + 2, ty, x0, wv, win, lam, sc, hf, op);
    conv_step<S, PH0>(ip, z0 + 3, ty, x0, wv, win, lam, sc, hf, op);
}

// z split into 4 chunks of 4 -> grid 512 blocks.
template <int S, int CPB>
__global__ __launch_bounds__(256) void dwconv_soft_chunk_k(
    const float* __restrict__ in, const float* __restrict__ wt,
    const float* __restrict__ wscale, const float* __restrict__ lambd_p,
    float* __restrict__ out) {
    constexpr int TX = S / 4;
    int tid = threadIdx.x;
    int tx  = tid % TX;
    int ty  = (tid / TX) % S;
    int cs  = tid / (TX * S);
    int zc  = blockIdx.x & 3;
    int cg  = blockIdx.x >> 2;
    int cc  = cg * CPB + cs;
    const float* ip = in + (long)cc * (S * S * S);
    float* op       = out + (long)cc * (S * S * S);
    float wv[27];
#pragma unroll
    for (int k = 0; k < 27; ++k) wv[k] = wt[cc * 27 + k];
    float lam = *lambd_p;
    float sc  = wscale[cc];
    bool hf   = (cc & 7) != 0;
    int x0    = 4 * tx;

    float win[3][3][6];
    switch (zc) {
        case 0:  run_chunk<S, 0>(ip, 0,  ty, x0, wv, win, lam, sc, hf, op); break;
        case 1:  run_chunk<S, 1>(ip, 4,  ty, x0, wv, win, lam, sc, hf, op); break;
        case 2:  run_chunk<S, 2>(ip, 8,  ty, x0, wv, win, lam, sc, hf, op); break;
        default: run_chunk<S, 0>(ip, 12, ty, x0, wv, win, lam, sc, hf, op); break;
    }
}

// ========== Final: LDS-tiled base conv + level-1 idwt + level-0 idwt =======
// final_k2, settled local optimum (90 µs). R1 (smaller tile) and R4 (512t
// same tile) both doubled HBM traffic — traffic term dominates; do not touch.
__global__ __launch_bounds__(256, 3) void final_k2(
    const float* __restrict__ x, const float* __restrict__ t0,
    const float* __restrict__ t1, const float* __restrict__ bw,
    const float* __restrict__ bb, const float* __restrict__ bscale,
    float* __restrict__ out) {
    __shared__ float xs[18 * 10 * 67];
    int bx = blockIdx.x;
    int c  = bx >> 5;
    int ti = bx & 31;
    int dt = ti >> 3;  // z tile (16 thick)
    int ht = ti & 7;   // y tile (8 thick)
    const float* xc = x + ((long)c << 18);
    int zg0 = 16 * dt - 1, yg0 = 8 * ht - 1;
    for (int i = threadIdx.x; i < 18 * 10 * 66; i += 256) {
        int pz = i / 660;
        int r  = i - pz * 660;
        int py = r / 66;
        int px = r - py * 66;
        int zg = zg0 + pz, yg = yg0 + py, xg = px - 1;
        bool ok = ((unsigned)zg < 64u) && ((unsigned)yg < 64u) && ((unsigned)xg < 64u);
        xs[(pz * 10 + py) * 67 + px] = ok ? xc[(zg << 12) + (yg << 6) + xg] : 0.f;
    }
    const float* wp0 = bw + c * 27;
    float wv[27];
#pragma unroll
    for (int k = 0; k < 27; ++k) wv[k] = wp0[k];
    float bias = bb[c], scl = bscale[c];
    __syncthreads();

    int tid = threadIdx.x;
    int wc  = tid & 7;         // x chunk: cells w0..w0+3
    int hc  = (tid >> 3) & 3;  // h cell in tile
    int dc  = tid >> 5;        // d cell in tile
    int d   = dt * 8 + dc;
    int h   = ht * 4 + hc;
    int w0  = wc * 4;

    float acc[2][2][8];
#pragma unroll
    for (int oz = 0; oz < 2; ++oz)
#pragma unroll
        for (int oy = 0; oy < 2; ++oy)
#pragma unroll
            for (int m = 0; m < 8; ++m) acc[oz][oy][m] = 0.f;

#pragma unroll
    for (int pz = 0; pz < 4; ++pz) {
        float r[4][10];
#pragma unroll
        for (int py = 0; py < 4; ++py)
#pragma unroll
            for (int k = 0; k < 10; ++k)
                r[py][k] = xs[((2 * dc + pz) * 10 + (2 * hc + py)) * 67 + 8 * wc + k];
#pragma unroll
        for (int oz = 0; oz < 2; ++oz) {
            int kz = pz - oz;
            if (kz >= 0 && kz <= 2) {
#pragma unroll
                for (int py = 0; py < 4; ++py)
#pragma unroll
                    for (int oy = 0; oy < 2; ++oy) {
                        int ky = py - oy;
                        if (ky >= 0 && ky <= 2) {
#pragma unroll
                            for (int kx = 0; kx < 3; ++kx) {
                                float wgt = wv[kz * 9 + ky * 3 + kx];
#pragma unroll
                                for (int m = 0; m < 8; ++m)
                                    acc[oz][oy][m] += r[py][m + kx] * wgt;
                            }
                        }
                    }
            }
        }
    }

    // epilogue: t0 (float4/band) + t1 idwt into band0, haar_inv, store
    int cell0 = (d << 10) + (h << 5) + w0;
    float4 t0v[8];
#pragma unroll
    for (int f = 0; f < 8; ++f)
        t0v[f] = *(const float4*)(t0 + (((long)(c * 8 + f)) << 15) + cell0);
    int s1b = ((d >> 1) * 16 + (h >> 1)) * 16 + (w0 >> 1);
    float2 t1v[8];
#pragma unroll
    for (int f = 0; f < 8; ++f)
        t1v[f] = *(const float2*)(t1 + ((c * 8 + f) << 12) + s1b);

#pragma unroll
    for (int j = 0; j < 4; ++j) {
        int w = w0 + j;
        float tf[8];
#pragma unroll
        for (int f = 0; f < 8; ++f) tf[f] = ((const float*)&t0v[f])[j];
        float add = 0.f;
#pragma unroll
        for (int f = 0; f < 8; ++f) {
            float v  = (j >> 1) ? t1v[f].y : t1v[f].x;
            float sg = 1.f;
            if ((f & 4) && (d & 1)) sg = -sg;
            if ((f & 2) && (h & 1)) sg = -sg;
            if ((f & 1) && (j & 1)) sg = -sg;
            add += sg * v;
        }
        tf[0] += add * SQ3F;
        float contrib[8];
        haar_inv(tf, contrib);
#pragma unroll
        for (int oz = 0; oz < 2; ++oz)
#pragma unroll
            for (int oy = 0; oy < 2; ++oy) {
                float2 rr;
                rr.x = (acc[oz][oy][2 * j] + bias) * scl + contrib[oz * 4 + oy * 2];
                rr.y = (acc[oz][oy][2 * j + 1] + bias) * scl +
                       contrib[oz * 4 + oy * 2 + 1];
                *(float2*)(out + ((long)c << 18) + ((2 * d + oz) << 12) +
                           ((2 * h + oy) << 6) + 2 * w) = rr;
            }
    }
}

extern "C" void kernel_launch(void* const* d_in, const int* in_sizes, int n_in,
                              void* d_out, int out_size, void* d_ws, size_t ws_size,
                              hipStream_t stream) {
    const float* x      = (const float*)d_in[0];
    const float* base_w = (const float*)d_in[1];
    const float* base_b = (const float*)d_in[2];
    const float* base_s = (const float*)d_in[3];
    const float* w0     = (const float*)d_in[4];
    const float* w1     = (const float*)d_in[5];
    const float* ws0    = (const float*)d_in[6];
    const float* ws1    = (const float*)d_in[7];
    const float* lambd  = (const float*)d_in[8];
    float* out = (float*)d_out;

    // Workspace (floats): ll 2.1M | t0 16.8M | cx1 2.1M | t1 2.1M
    float* ll  = (float*)d_ws;
    float* t0  = ll + 2097152;
    float* cx1 = t0 + 16777216;
    float* t1  = cx1 + 2097152;

    // Level 0 fused: x -> t0 (conv+soft+scale, all 8 bands) + raw LL
    fused_l0_k<<<1024, 512, 0, stream>>>(x, w0, ws0, lambd, t0, ll);
    // Level 1
    dwt3_k<16><<<1024, 256, 0, stream>>>(ll, 32768, cx1);
    dwconv_soft_chunk_k<16, 4><<<512, 256, 0, stream>>>(cx1, w1, ws1, lambd, t1);
    // Final: base conv + level-1 idwt (fused) + level-0 idwt
    final_k2<<<2048, 256, 0, stream>>>(x, t0, t1, base_w, base_b, base_s, out);
}

// Round 6
// 249.605 us; speedup vs baseline: 1.1976x; 1.0071x over previous
//
#include <hip/hip_runtime.h>

#define SQ3F 0.35355339059327379f

__device__ __forceinline__ float rfl(float v) {
    return __int_as_float(__builtin_amdgcn_readfirstlane(__float_as_int(v)));
}

// Forward 2x2x2 Haar butterfly. v index = z*4+y*2+x. o index = fz*4+fy*2+fx.
__device__ __forceinline__ void haar_fwd(const float v[8], float o[8]) {
    float ax[8];
#pragma unroll
    for (int i = 0; i < 4; ++i) {
        float a = v[2 * i], b = v[2 * i + 1];
        ax[2 * i]     = a + b;
        ax[2 * i + 1] = b - a;
    }
    float ay[8];
#pragma unroll
    for (int z = 0; z < 2; ++z)
#pragma unroll
        for (int bx = 0; bx < 2; ++bx) {
            float a = ax[z * 4 + bx], b = ax[z * 4 + 2 + bx];
            ay[z * 4 + bx]     = a + b;
            ay[z * 4 + 2 + bx] = b - a;
        }
#pragma unroll
    for (int j = 0; j < 4; ++j) {
        float a = ay[j], b = ay[4 + j];
        o[j]     = (a + b) * SQ3F;
        o[4 + j] = (b - a) * SQ3F;
    }
}

// Inverse Haar. t index = fz*4+fy*2+fx. o index = z*4+y*2+x.
__device__ __forceinline__ void haar_inv(const float t[8], float o[8]) {
    float az[8];
#pragma unroll
    for (int j = 0; j < 4; ++j) {
        float lo = t[j], hi = t[4 + j];
        az[j]     = lo + hi;
        az[4 + j] = lo - hi;
    }
    float ay[8];
#pragma unroll
    for (int z = 0; z < 2; ++z)
#pragma unroll
        for (int bx = 0; bx < 2; ++bx) {
            float lo = az[z * 4 + bx], hi = az[z * 4 + 2 + bx];
            ay[z * 4 + bx]     = lo + hi;
            ay[z * 4 + 2 + bx] = lo - hi;
        }
#pragma unroll
    for (int i = 0; i < 4; ++i) {
        float lo = ay[2 * i], hi = ay[2 * i + 1];
        o[2 * i]     = (lo + hi) * SQ3F;
        o[2 * i + 1] = (lo - hi) * SQ3F;
    }
}

// ============ Fused level-0: DWT + depthwise conv + soft-threshold =========
// R6: R5 structure + two structural additions:
//  - level-1 DWT fused: each block's z-pair (z0,z0+1) is exactly one level-1
//    cell layer; staging threads keep raw-LL in regs, y-parity partner via
//    __shfl_xor(.,16) (same wave), haar_fwd, write cx1 directly.
//    Eliminates dwt3_k and the ll buffer (16 MB traffic + one dispatch).
//  - XCD-chunked blockIdx swizzle: adjacent slabs (which share 50% of their
//    staged planes as z-halo) land on the same XCD -> halo reads L2-hit.
__global__ __launch_bounds__(512, 6) void fused_l0_k(
    const float* __restrict__ x, const float* __restrict__ wt,
    const float* __restrict__ wscale, const float* __restrict__ lambd_p,
    float* __restrict__ t0, float* __restrict__ cx1) {
    __shared__ __align__(16) float pl[8][32][36];
    int bx   = ((blockIdx.x & 7) << 7) + (blockIdx.x >> 3);  // XCD-chunked
    int slab = bx & 15;
    int c    = bx >> 4;
    int z0   = slab * 2;
    int tid  = threadIdx.x;

    // zero the x-pad columns once (512 pad slots, one per thread)
    {
        int fi   = tid >> 6;
        int rowi = (tid >> 1) & 31;
        pl[fi][rowi][(tid & 1) * 33] = 0.f;
    }

    int f    = __builtin_amdgcn_readfirstlane(tid >> 6);  // band, wave-uniform
    int lane = tid & 63;
    int cty  = lane >> 1;         // conv row 0..31
    int cx0i = (lane & 1) * 16;   // 16-wide x chunk
    int cc   = c * 8 + f;         // wave-uniform
    float wv[27];
    const float* wp = wt + cc * 27;
#pragma unroll
    for (int k = 0; k < 27; ++k) wv[k] = rfl(wp[k]);  // SGPRs
    float lam = rfl(*lambd_p);
    float sc  = rfl(wscale[cc]);

    const float* xc = x + ((long)c << 18);

    float acc[2][16];
#pragma unroll
    for (int s = 0; s < 2; ++s)
#pragma unroll
        for (int j = 0; j < 16; ++j) acc[s][j] = 0.f;

    float llq00 = 0.f, llq01 = 0.f;  // raw LL of plane z0 (this thread's 2 cells)

    // pp fully unrolled so acc/ring indices are compile-time constants.
#pragma unroll
    for (int pp = 0; pp < 4; ++pp) {
        int p       = z0 - 1 + pp;
        bool pvalid = (p >= 0) && (p <= 31);  // wave-uniform
        __syncthreads();
        if (pvalid) {
            // DWT plane p -> LDS (1024 cells, 2 x-adjacent cells per thread;
            // global reads are float4 = both cells' x-pairs in one load)
            int cell = 2 * tid;
            int y    = cell >> 5;
            int xx   = cell & 31;  // even
            float v0[8], v1[8];
#pragma unroll
            for (int z = 0; z < 2; ++z)
#pragma unroll
                for (int yy = 0; yy < 2; ++yy) {
                    float4 q = *(const float4*)(xc + (((2 * p + z) << 6) +
                                                      (2 * y + yy)) * 64 + 2 * xx);
                    v0[z * 4 + yy * 2]     = q.x;
                    v0[z * 4 + yy * 2 + 1] = q.y;
                    v1[z * 4 + yy * 2]     = q.z;
                    v1[z * 4 + yy * 2 + 1] = q.w;
                }
            float o0[8], o1[8];
            haar_fwd(v0, o0);
            haar_fwd(v1, o1);
#pragma unroll
            for (int k = 0; k < 8; ++k) {
                pl[k][y][xx + 1] = o0[k];
                pl[k][y][xx + 2] = o1[k];
            }
            if (pp == 1) {  // plane z0: stash raw LL for level-1 DWT
                llq00 = o0[0];
                llq01 = o1[0];
            }
            if (pp == 2) {  // plane z0+1: complete the level-1 cell, write cx1
                float l10 = o0[0], l11 = o1[0];
                // y-parity partner = lane^16 (same wave; pvalid wave-uniform)
                float p00 = __shfl_xor(llq00, 16);
                float p01 = __shfl_xor(llq01, 16);
                float p10 = __shfl_xor(l10, 16);
                float p11 = __shfl_xor(l11, 16);
                int yp = (tid >> 4) & 1;  // y parity
                float v[8];  // v[z*4 + yy*2 + xp]
                if (yp == 0) {
                    v[0] = llq00; v[1] = llq01; v[2] = p00; v[3] = p01;
                    v[4] = l10;   v[5] = l11;   v[6] = p10; v[7] = p11;
                } else {
                    v[0] = p00;   v[1] = p01;   v[2] = llq00; v[3] = llq01;
                    v[4] = p10;   v[5] = p11;   v[6] = l10;   v[7] = l11;
                }
                float o[8];
                haar_fwd(v, o);
                int d  = z0 >> 1;
                int hy = (tid >> 4) >> 1;   // y/2, 0..15
                int wx = tid & 15;          // xx/2
                int sA = (d * 16 + hy) * 16 + wx;
                int f0 = yp * 4;  // even-y writes bands 0-3, odd-y bands 4-7
#pragma unroll
                for (int q = 0; q < 4; ++q)
                    cx1[((c * 8 + f0 + q) << 12) + sA] = o[f0 + q];
            }
        }
        __syncthreads();
        if (pvalid) {
            // fold plane p into pending outputs zc = p+1-dz (rel = pp-dz)
#pragma unroll
            for (int dy = 0; dy < 3; ++dy) {
                int yy = cty - 1 + dy;
                if ((unsigned)yy < 32u) {
                    float r[18];
                    {
                        const float* rp = &pl[f][yy][cx0i];
                        float4 a0 = *(const float4*)(rp);
                        float4 a1 = *(const float4*)(rp + 4);
                        float4 a2 = *(const float4*)(rp + 8);
                        float4 a3 = *(const float4*)(rp + 12);
                        float2 a4 = *(const float2*)(rp + 16);
                        r[0]  = a0.x; r[1]  = a0.y; r[2]  = a0.z; r[3]  = a0.w;
                        r[4]  = a1.x; r[5]  = a1.y; r[6]  = a1.z; r[7]  = a1.w;
                        r[8]  = a2.x; r[9]  = a2.y; r[10] = a2.z; r[11] = a2.w;
                        r[12] = a3.x; r[13] = a3.y; r[14] = a3.z; r[15] = a3.w;
                        r[16] = a4.x; r[17] = a4.y;
                    }
#pragma unroll
                    for (int dz = 0; dz < 3; ++dz) {
                        int rel = pp - dz;
                        if (rel >= 0 && rel <= 1) {  // compile-time
#pragma unroll
                            for (int dx = 0; dx < 3; ++dx) {
                                float wgt = wv[dz * 9 + dy * 3 + dx];
#pragma unroll
                                for (int j = 0; j < 16; ++j)
                                    acc[rel][j] += r[dx + j] * wgt;
                            }
                        }
                    }
                }
            }
        }
        // finalize output zc = z0+rel (rel = pp-2) — needs planes zc-1..zc+1
        {
            int rel = pp - 2;
            if (rel >= 0 && rel <= 1) {  // compile-time
                int zc = z0 + rel;
                // for slab 15, zc=31 finalizes at pp=3 even though p=32 skipped
                float res[16];
#pragma unroll
                for (int j = 0; j < 16; ++j) {
                    float t = acc[rel][j];
                    if (f != 0) {
                        float a = fabsf(t) - lam;
                        t       = a > 0.f ? copysignf(a, t) : 0.f;
                    }
                    res[j]      = t * sc;
                    acc[rel][j] = 0.f;
                }
                float* op = t0 + ((long)cc << 15) + (zc << 10) + cty * 32 + cx0i;
#pragma unroll
                for (int q = 0; q < 4; ++q)
                    *(float4*)(op + q * 4) = float4{res[q * 4], res[q * 4 + 1],
                                                    res[q * 4 + 2], res[q * 4 + 3]};
            }
        }
    }
}

// ===================== Level-1 conv kernel =======================
template <int S, int PH>
__device__ __forceinline__ void conv_step(const float* __restrict__ ip, int zo,
                                          int ty, int x0,
                                          const float* __restrict__ wv,
                                          float win[3][3][6], float lam, float sc,
                                          bool hf, float* __restrict__ op) {
    constexpr int sPrev = (PH + 2) % 3;
    constexpr int sCur  = PH;
    constexpr int sNext = (PH + 1) % 3;
    {
        int zz = zo + 1;
        bool zok = zz < S;
        const float* pp = ip + zz * S * S;
#pragma unroll
        for (int dy = 0; dy < 3; ++dy) {
            int yy  = ty - 1 + dy;
            bool yok = zok && ((unsigned)yy < (unsigned)S);
            const float* rp = pp + yy * S;
            win[sNext][dy][0] = (yok && x0 > 0) ? rp[x0 - 1] : 0.f;
            float4 m = yok ? *(const float4*)(rp + x0) : float4{0.f, 0.f, 0.f, 0.f};
            win[sNext][dy][1] = m.x;
            win[sNext][dy][2] = m.y;
            win[sNext][dy][3] = m.z;
            win[sNext][dy][4] = m.w;
            win[sNext][dy][5] = (yok && (x0 + 4 < S)) ? rp[x0 + 4] : 0.f;
        }
    }
    float acc[4] = {0.f, 0.f, 0.f, 0.f};
#pragma unroll
    for (int dz = 0; dz < 3; ++dz) {
        const float(*wp)[6] = (dz == 0) ? win[sPrev] : (dz == 1) ? win[sCur] : win[sNext];
#pragma unroll
        for (int dy = 0; dy < 3; ++dy)
#pragma unroll
            for (int dx = 0; dx < 3; ++dx) {
                float wgt = wv[dz * 9 + dy * 3 + dx];
#pragma unroll
                for (int j = 0; j < 4; ++j) acc[j] += wp[dy][dx + j] * wgt;
            }
    }
    float4 r;
    float* rr = (float*)&r;
#pragma unroll
    for (int j = 0; j < 4; ++j) {
        float t = acc[j];
        if (hf) {
            float a = fabsf(t) - lam;
            t       = a > 0.f ? copysignf(a, t) : 0.f;
        }
        rr[j] = t * sc;
    }
    *(float4*)(op + (zo * S + ty) * S + x0) = r;
}

// load plane z into win[SLOT] (zeros if z out of range)
template <int S, int SLOT>
__device__ __forceinline__ void load_win_plane(const float* __restrict__ ip,
                                               int z, int ty, int x0,
                                               float win[3][3][6]) {
    bool zok = ((unsigned)z < (unsigned)S);
    const float* pp = ip + z * S * S;
#pragma unroll
    for (int dy = 0; dy < 3; ++dy) {
        int yy  = ty - 1 + dy;
        bool yok = zok && ((unsigned)yy < (unsigned)S);
        const float* rp = pp + yy * S;
        win[SLOT][dy][0] = (yok && x0 > 0) ? rp[x0 - 1] : 0.f;
        float4 m = yok ? *(const float4*)(rp + x0) : float4{0.f, 0.f, 0.f, 0.f};
        win[SLOT][dy][1] = m.x;
        win[SLOT][dy][2] = m.y;
        win[SLOT][dy][3] = m.z;
        win[SLOT][dy][4] = m.w;
        win[SLOT][dy][5] = (yok && (x0 + 4 < S)) ? rp[x0 + 4] : 0.f;
    }
}

// 4-z-step chunk starting at z0; buffer slot of plane q is q%3, PH0 = z0%3.
template <int S, int PH0>
__device__ __forceinline__ void run_chunk(const float* __restrict__ ip, int z0,
                                          int ty, int x0,
                                          const float* __restrict__ wv,
                                          float win[3][3][6], float lam, float sc,
                                          bool hf, float* __restrict__ op) {
    load_win_plane<S, (PH0 + 2) % 3>(ip, z0 - 1, ty, x0, win);
    load_win_plane<S, PH0>(ip, z0, ty, x0, win);
    conv_step<S, PH0>(ip, z0, ty, x0, wv, win, lam, sc, hf, op);
    conv_step<S, (PH0 + 1) % 3>(ip, z0 + 1, ty, x0, wv, win, lam, sc, hf, op);
    conv_step<S, (PH0 + 2) % 3>(ip, z0 + 2, ty, x0, wv, win, lam, sc, hf, op);
    conv_step<S, PH0>(ip, z0 + 3, ty, x0, wv, win, lam, sc, hf, op);
}

// z split into 4 chunks of 4 -> grid 512 blocks; XCD-chunked swizzle so
// adjacent z-chunks (shared halo planes) land on the same XCD's L2.
template <int S, int CPB>
__global__ __launch_bounds__(256) void dwconv_soft_chunk_k(
    const float* __restrict__ in, const float* __restrict__ wt,
    const float* __restrict__ wscale, const float* __restrict__ lambd_p,
    float* __restrict__ out) {
    constexpr int TX = S / 4;
    int bxl = ((blockIdx.x & 7) << 6) + (blockIdx.x >> 3);  // XCD-chunked
    int tid = threadIdx.x;
    int tx  = tid % TX;
    int ty  = (tid / TX) % S;
    int cs  = tid / (TX * S);
    int zc  = bxl & 3;
    int cg  = bxl >> 2;
    int cc  = cg * CPB + cs;
    const float* ip = in + (long)cc * (S * S * S);
    float* op       = out + (long)cc * (S * S * S);
    float wv[27];
#pragma unroll
    for (int k = 0; k < 27; ++k) wv[k] = wt[cc * 27 + k];
    float lam = *lambd_p;
    float sc  = wscale[cc];
    bool hf   = (cc & 7) != 0;
    int x0    = 4 * tx;

    float win[3][3][6];
    switch (zc) {
        case 0:  run_chunk<S, 0>(ip, 0,  ty, x0, wv, win, lam, sc, hf, op); break;
        case 1:  run_chunk<S, 1>(ip, 4,  ty, x0, wv, win, lam, sc, hf, op); break;
        case 2:  run_chunk<S, 2>(ip, 8,  ty, x0, wv, win, lam, sc, hf, op); break;
        default: run_chunk<S, 0>(ip, 12, ty, x0, wv, win, lam, sc, hf, op); break;
    }
}

// ========== Final: LDS-tiled base conv + level-1 idwt + level-0 idwt =======
// final_k2, settled local optimum (90 µs). R1 (smaller tile) and R4 (512t
// same tile) both doubled HBM traffic — traffic term dominates; do not touch.
__global__ __launch_bounds__(256, 3) void final_k2(
    const float* __restrict__ x, const float* __restrict__ t0,
    const float* __restrict__ t1, const float* __restrict__ bw,
    const float* __restrict__ bb, const float* __restrict__ bscale,
    float* __restrict__ out) {
    __shared__ float xs[18 * 10 * 67];
    int bx = blockIdx.x;
    int c  = bx >> 5;
    int ti = bx & 31;
    int dt = ti >> 3;  // z tile (16 thick)
    int ht = ti & 7;   // y tile (8 thick)
    const float* xc = x + ((long)c << 18);
    int zg0 = 16 * dt - 1, yg0 = 8 * ht - 1;
    for (int i = threadIdx.x; i < 18 * 10 * 66; i += 256) {
        int pz = i / 660;
        int r  = i - pz * 660;
        int py = r / 66;
        int px = r - py * 66;
        int zg = zg0 + pz, yg = yg0 + py, xg = px - 1;
        bool ok = ((unsigned)zg < 64u) && ((unsigned)yg < 64u) && ((unsigned)xg < 64u);
        xs[(pz * 10 + py) * 67 + px] = ok ? xc[(zg << 12) + (yg << 6) + xg] : 0.f;
    }
    const float* wp0 = bw + c * 27;
    float wv[27];
#pragma unroll
    for (int k = 0; k < 27; ++k) wv[k] = wp0[k];
    float bias = bb[c], scl = bscale[c];
    __syncthreads();

    int tid = threadIdx.x;
    int wc  = tid & 7;         // x chunk: cells w0..w0+3
    int hc  = (tid >> 3) & 3;  // h cell in tile
    int dc  = tid >> 5;        // d cell in tile
    int d   = dt * 8 + dc;
    int h   = ht * 4 + hc;
    int w0  = wc * 4;

    float acc[2][2][8];
#pragma unroll
    for (int oz = 0; oz < 2; ++oz)
#pragma unroll
        for (int oy = 0; oy < 2; ++oy)
#pragma unroll
            for (int m = 0; m < 8; ++m) acc[oz][oy][m] = 0.f;

#pragma unroll
    for (int pz = 0; pz < 4; ++pz) {
        float r[4][10];
#pragma unroll
        for (int py = 0; py < 4; ++py)
#pragma unroll
            for (int k = 0; k < 10; ++k)
                r[py][k] = xs[((2 * dc + pz) * 10 + (2 * hc + py)) * 67 + 8 * wc + k];
#pragma unroll
        for (int oz = 0; oz < 2; ++oz) {
            int kz = pz - oz;
            if (kz >= 0 && kz <= 2) {
#pragma unroll
                for (int py = 0; py < 4; ++py)
#pragma unroll
                    for (int oy = 0; oy < 2; ++oy) {
                        int ky = py - oy;
                        if (ky >= 0 && ky <= 2) {
#pragma unroll
                            for (int kx = 0; kx < 3; ++kx) {
                                float wgt = wv[kz * 9 + ky * 3 + kx];
#pragma unroll
                                for (int m = 0; m < 8; ++m)
                                    acc[oz][oy][m] += r[py][m + kx] * wgt;
                            }
                        }
                    }
            }
        }
    }

    // epilogue: t0 (float4/band) + t1 idwt into band0, haar_inv, store
    int cell0 = (d << 10) + (h << 5) + w0;
    float4 t0v[8];
#pragma unroll
    for (int f = 0; f < 8; ++f)
        t0v[f] = *(const float4*)(t0 + (((long)(c * 8 + f)) << 15) + cell0);
    int s1b = ((d >> 1) * 16 + (h >> 1)) * 16 + (w0 >> 1);
    float2 t1v[8];
#pragma unroll
    for (int f = 0; f < 8; ++f)
        t1v[f] = *(const float2*)(t1 + ((c * 8 + f) << 12) + s1b);

#pragma unroll
    for (int j = 0; j < 4; ++j) {
        int w = w0 + j;
        float tf[8];
#pragma unroll
        for (int f = 0; f < 8; ++f) tf[f] = ((const float*)&t0v[f])[j];
        float add = 0.f;
#pragma unroll
        for (int f = 0; f < 8; ++f) {
            float v  = (j >> 1) ? t1v[f].y : t1v[f].x;
            float sg = 1.f;
            if ((f & 4) && (d & 1)) sg = -sg;
            if ((f & 2) && (h & 1)) sg = -sg;
            if ((f & 1) && (j & 1)) sg = -sg;
            add += sg * v;
        }
        tf[0] += add * SQ3F;
        float contrib[8];
        haar_inv(tf, contrib);
#pragma unroll
        for (int oz = 0; oz < 2; ++oz)
#pragma unroll
            for (int oy = 0; oy < 2; ++oy) {
                float2 rr;
                rr.x = (acc[oz][oy][2 * j] + bias) * scl + contrib[oz * 4 + oy * 2];
                rr.y = (acc[oz][oy][2 * j + 1] + bias) * scl +
                       contrib[oz * 4 + oy * 2 + 1];
                *(float2*)(out + ((long)c << 18) + ((2 * d + oz) << 12) +
                           ((2 * h + oy) << 6) + 2 * w) = rr;
            }
    }
}

extern "C" void kernel_launch(void* const* d_in, const int* in_sizes, int n_in,
                              void* d_out, int out_size, void* d_ws, size_t ws_size,
                              hipStream_t stream) {
    const float* x      = (const float*)d_in[0];
    const float* base_w = (const float*)d_in[1];
    const float* base_b = (const float*)d_in[2];
    const float* base_s = (const float*)d_in[3];
    const float* w0     = (const float*)d_in[4];
    const float* w1     = (const float*)d_in[5];
    const float* ws0    = (const float*)d_in[6];
    const float* ws1    = (const float*)d_in[7];
    const float* lambd  = (const float*)d_in[8];
    float* out = (float*)d_out;

    // Workspace (floats): t0 16.8M | cx1 2.1M | t1 2.1M  (ll eliminated)
    float* t0  = (float*)d_ws;
    float* cx1 = t0 + 16777216;
    float* t1  = cx1 + 2097152;

    // Level 0 fused: x -> t0 (conv+soft+scale, all 8 bands) + level-1 DWT cx1
    fused_l0_k<<<1024, 512, 0, stream>>>(x, w0, ws0, lambd, t0, cx1);
    // Level 1 conv+soft
    dwconv_soft_chunk_k<16, 4><<<512, 256, 0, stream>>>(cx1, w1, ws1, lambd, t1);
    // Final: base conv + level-1 idwt (fused) + level-0 idwt
    final_k2<<<2048, 256, 0, stream>>>(x, t0, t1, base_w, base_b, base_s, out);
}

// Round 7
// 238.927 us; speedup vs baseline: 1.2512x; 1.0447x over previous
//
#include <hip/hip_runtime.h>

#define SQ3F 0.35355339059327379f

__device__ __forceinline__ float rfl(float v) {
    return __int_as_float(__builtin_amdgcn_readfirstlane(__float_as_int(v)));
}

// Forward 2x2x2 Haar butterfly. v index = z*4+y*2+x. o index = fz*4+fy*2+fx.
__device__ __forceinline__ void haar_fwd(const float v[8], float o[8]) {
    float ax[8];
#pragma unroll
    for (int i = 0; i < 4; ++i) {
        float a = v[2 * i], b = v[2 * i + 1];
        ax[2 * i]     = a + b;
        ax[2 * i + 1] = b - a;
    }
    float ay[8];
#pragma unroll
    for (int z = 0; z < 2; ++z)
#pragma unroll
        for (int bx = 0; bx < 2; ++bx) {
            float a = ax[z * 4 + bx], b = ax[z * 4 + 2 + bx];
            ay[z * 4 + bx]     = a + b;
            ay[z * 4 + 2 + bx] = b - a;
        }
#pragma unroll
    for (int j = 0; j < 4; ++j) {
        float a = ay[j], b = ay[4 + j];
        o[j]     = (a + b) * SQ3F;
        o[4 + j] = (b - a) * SQ3F;
    }
}

// Inverse Haar. t index = fz*4+fy*2+fx. o index = z*4+y*2+x.
__device__ __forceinline__ void haar_inv(const float t[8], float o[8]) {
    float az[8];
#pragma unroll
    for (int j = 0; j < 4; ++j) {
        float lo = t[j], hi = t[4 + j];
        az[j]     = lo + hi;
        az[4 + j] = lo - hi;
    }
    float ay[8];
#pragma unroll
    for (int z = 0; z < 2; ++z)
#pragma unroll
        for (int bx = 0; bx < 2; ++bx) {
            float lo = az[z * 4 + bx], hi = az[z * 4 + 2 + bx];
            ay[z * 4 + bx]     = lo + hi;
            ay[z * 4 + 2 + bx] = lo - hi;
        }
#pragma unroll
    for (int i = 0; i < 4; ++i) {
        float lo = ay[2 * i], hi = ay[2 * i + 1];
        o[2 * i]     = (lo + hi) * SQ3F;
        o[2 * i + 1] = (lo - hi) * SQ3F;
    }
}

// ============ Fused level-0: DWT + depthwise conv + soft-threshold =========
// (R6 version, verified: level-1 DWT fused via __shfl_xor, dwt3_k/ll
// eliminated; XCD-chunked swizzle.)
__global__ __launch_bounds__(512, 6) void fused_l0_k(
    const float* __restrict__ x, const float* __restrict__ wt,
    const float* __restrict__ wscale, const float* __restrict__ lambd_p,
    float* __restrict__ t0, float* __restrict__ cx1) {
    __shared__ __align__(16) float pl[8][32][36];
    int bx   = ((blockIdx.x & 7) << 7) + (blockIdx.x >> 3);  // XCD-chunked
    int slab = bx & 15;
    int c    = bx >> 4;
    int z0   = slab * 2;
    int tid  = threadIdx.x;

    // zero the x-pad columns once (512 pad slots, one per thread)
    {
        int fi   = tid >> 6;
        int rowi = (tid >> 1) & 31;
        pl[fi][rowi][(tid & 1) * 33] = 0.f;
    }

    int f    = __builtin_amdgcn_readfirstlane(tid >> 6);  // band, wave-uniform
    int lane = tid & 63;
    int cty  = lane >> 1;         // conv row 0..31
    int cx0i = (lane & 1) * 16;   // 16-wide x chunk
    int cc   = c * 8 + f;         // wave-uniform
    float wv[27];
    const float* wp = wt + cc * 27;
#pragma unroll
    for (int k = 0; k < 27; ++k) wv[k] = rfl(wp[k]);  // SGPRs
    float lam = rfl(*lambd_p);
    float sc  = rfl(wscale[cc]);

    const float* xc = x + ((long)c << 18);

    float acc[2][16];
#pragma unroll
    for (int s = 0; s < 2; ++s)
#pragma unroll
        for (int j = 0; j < 16; ++j) acc[s][j] = 0.f;

    float llq00 = 0.f, llq01 = 0.f;  // raw LL of plane z0 (this thread's 2 cells)

    // pp fully unrolled so acc/ring indices are compile-time constants.
#pragma unroll
    for (int pp = 0; pp < 4; ++pp) {
        int p       = z0 - 1 + pp;
        bool pvalid = (p >= 0) && (p <= 31);  // wave-uniform
        __syncthreads();
        if (pvalid) {
            // DWT plane p -> LDS (1024 cells, 2 x-adjacent cells per thread;
            // global reads are float4 = both cells' x-pairs in one load)
            int cell = 2 * tid;
            int y    = cell >> 5;
            int xx   = cell & 31;  // even
            float v0[8], v1[8];
#pragma unroll
            for (int z = 0; z < 2; ++z)
#pragma unroll
                for (int yy = 0; yy < 2; ++yy) {
                    float4 q = *(const float4*)(xc + (((2 * p + z) << 6) +
                                                      (2 * y + yy)) * 64 + 2 * xx);
                    v0[z * 4 + yy * 2]     = q.x;
                    v0[z * 4 + yy * 2 + 1] = q.y;
                    v1[z * 4 + yy * 2]     = q.z;
                    v1[z * 4 + yy * 2 + 1] = q.w;
                }
            float o0[8], o1[8];
            haar_fwd(v0, o0);
            haar_fwd(v1, o1);
#pragma unroll
            for (int k = 0; k < 8; ++k) {
                pl[k][y][xx + 1] = o0[k];
                pl[k][y][xx + 2] = o1[k];
            }
            if (pp == 1) {  // plane z0: stash raw LL for level-1 DWT
                llq00 = o0[0];
                llq01 = o1[0];
            }
            if (pp == 2) {  // plane z0+1: complete the level-1 cell, write cx1
                float l10 = o0[0], l11 = o1[0];
                // y-parity partner = lane^16 (same wave; pvalid wave-uniform)
                float p00 = __shfl_xor(llq00, 16);
                float p01 = __shfl_xor(llq01, 16);
                float p10 = __shfl_xor(l10, 16);
                float p11 = __shfl_xor(l11, 16);
                int yp = (tid >> 4) & 1;  // y parity
                float v[8];  // v[z*4 + yy*2 + xp]
                if (yp == 0) {
                    v[0] = llq00; v[1] = llq01; v[2] = p00; v[3] = p01;
                    v[4] = l10;   v[5] = l11;   v[6] = p10; v[7] = p11;
                } else {
                    v[0] = p00;   v[1] = p01;   v[2] = llq00; v[3] = llq01;
                    v[4] = p10;   v[5] = p11;   v[6] = l10;   v[7] = l11;
                }
                float o[8];
                haar_fwd(v, o);
                int d  = z0 >> 1;
                int hy = (tid >> 4) >> 1;   // y/2, 0..15
                int wx = tid & 15;          // xx/2
                int sA = (d * 16 + hy) * 16 + wx;
                int f0 = yp * 4;  // even-y writes bands 0-3, odd-y bands 4-7
#pragma unroll
                for (int q = 0; q < 4; ++q)
                    cx1[((c * 8 + f0 + q) << 12) + sA] = o[f0 + q];
            }
        }
        __syncthreads();
        if (pvalid) {
            // fold plane p into pending outputs zc = p+1-dz (rel = pp-dz)
#pragma unroll
            for (int dy = 0; dy < 3; ++dy) {
                int yy = cty - 1 + dy;
                if ((unsigned)yy < 32u) {
                    float r[18];
                    {
                        const float* rp = &pl[f][yy][cx0i];
                        float4 a0 = *(const float4*)(rp);
                        float4 a1 = *(const float4*)(rp + 4);
                        float4 a2 = *(const float4*)(rp + 8);
                        float4 a3 = *(const float4*)(rp + 12);
                        float2 a4 = *(const float2*)(rp + 16);
                        r[0]  = a0.x; r[1]  = a0.y; r[2]  = a0.z; r[3]  = a0.w;
                        r[4]  = a1.x; r[5]  = a1.y; r[6]  = a1.z; r[7]  = a1.w;
                        r[8]  = a2.x; r[9]  = a2.y; r[10] = a2.z; r[11] = a2.w;
                        r[12] = a3.x; r[13] = a3.y; r[14] = a3.z; r[15] = a3.w;
                        r[16] = a4.x; r[17] = a4.y;
                    }
#pragma unroll
                    for (int dz = 0; dz < 3; ++dz) {
                        int rel = pp - dz;
                        if (rel >= 0 && rel <= 1) {  // compile-time
#pragma unroll
                            for (int dx = 0; dx < 3; ++dx) {
                                float wgt = wv[dz * 9 + dy * 3 + dx];
#pragma unroll
                                for (int j = 0; j < 16; ++j)
                                    acc[rel][j] += r[dx + j] * wgt;
                            }
                        }
                    }
                }
            }
        }
        // finalize output zc = z0+rel (rel = pp-2) — needs planes zc-1..zc+1
        {
            int rel = pp - 2;
            if (rel >= 0 && rel <= 1) {  // compile-time
                int zc = z0 + rel;
                float res[16];
#pragma unroll
                for (int j = 0; j < 16; ++j) {
                    float t = acc[rel][j];
                    if (f != 0) {
                        float a = fabsf(t) - lam;
                        t       = a > 0.f ? copysignf(a, t) : 0.f;
                    }
                    res[j]      = t * sc;
                    acc[rel][j] = 0.f;
                }
                float* op = t0 + ((long)cc << 15) + (zc << 10) + cty * 32 + cx0i;
#pragma unroll
                for (int q = 0; q < 4; ++q)
                    *(float4*)(op + q * 4) = float4{res[q * 4], res[q * 4 + 1],
                                                    res[q * 4 + 2], res[q * 4 + 3]};
            }
        }
    }
}

// ===================== Level-1 conv kernel =======================
// R7: true software pipeline. win[4] ring (slot = plane & 3; all chunk
// starts are multiples of 4), plane z+2's load issued BEFORE computing
// step z -> load latency hides under the 108 FMAs of the current step.
// Previous version loaded plane z+1 and consumed it in the SAME step
// (load on the critical path of every step).
template <int S, int SLOT>
__device__ __forceinline__ void load_plane4(const float* __restrict__ ip,
                                            int z, int ty, int x0,
                                            float win[4][3][6]) {
    bool zok = ((unsigned)z < (unsigned)S);
    const float* pp = ip + z * S * S;
#pragma unroll
    for (int dy = 0; dy < 3; ++dy) {
        int yy  = ty - 1 + dy;
        bool yok = zok && ((unsigned)yy < (unsigned)S);
        const float* rp = pp + yy * S;
        win[SLOT][dy][0] = (yok && x0 > 0) ? rp[x0 - 1] : 0.f;
        float4 m = yok ? *(const float4*)(rp + x0) : float4{0.f, 0.f, 0.f, 0.f};
        win[SLOT][dy][1] = m.x;
        win[SLOT][dy][2] = m.y;
        win[SLOT][dy][3] = m.z;
        win[SLOT][dy][4] = m.w;
        win[SLOT][dy][5] = (yok && (x0 + 4 < S)) ? rp[x0 + 4] : 0.f;
    }
}

template <int S, int SP, int SC, int SN>
__device__ __forceinline__ void conv_compute(int zo, int ty, int x0,
                                             const float* __restrict__ wv,
                                             const float win[4][3][6], float lam,
                                             float sc, bool hf,
                                             float* __restrict__ op) {
    float acc[4] = {0.f, 0.f, 0.f, 0.f};
#pragma unroll
    for (int dz = 0; dz < 3; ++dz) {
        const float(*wp)[6] = (dz == 0) ? win[SP] : (dz == 1) ? win[SC] : win[SN];
#pragma unroll
        for (int dy = 0; dy < 3; ++dy)
#pragma unroll
            for (int dx = 0; dx < 3; ++dx) {
                float wgt = wv[dz * 9 + dy * 3 + dx];
#pragma unroll
                for (int j = 0; j < 4; ++j) acc[j] += wp[dy][dx + j] * wgt;
            }
    }
    float4 r;
    float* rr = (float*)&r;
#pragma unroll
    for (int j = 0; j < 4; ++j) {
        float t = acc[j];
        if (hf) {
            float a = fabsf(t) - lam;
            t       = a > 0.f ? copysignf(a, t) : 0.f;
        }
        rr[j] = t * sc;
    }
    *(float4*)(op + (zo * S + ty) * S + x0) = r;
}

// z split into 4 chunks of 4 -> grid 512 blocks; XCD-chunked swizzle.
template <int S, int CPB>
__global__ __launch_bounds__(256) void dwconv_soft_pipe_k(
    const float* __restrict__ in, const float* __restrict__ wt,
    const float* __restrict__ wscale, const float* __restrict__ lambd_p,
    float* __restrict__ out) {
    constexpr int TX = S / 4;
    int bxl = ((blockIdx.x & 7) << 6) + (blockIdx.x >> 3);  // XCD-chunked
    int tid = threadIdx.x;
    int tx  = tid % TX;
    int ty  = (tid / TX) % S;
    int cs  = tid / (TX * S);
    int zc  = bxl & 3;
    int cg  = bxl >> 2;
    int cc  = cg * CPB + cs;
    const float* ip = in + (long)cc * (S * S * S);
    float* op       = out + (long)cc * (S * S * S);
    float wv[27];
#pragma unroll
    for (int k = 0; k < 27; ++k) wv[k] = wt[cc * 27 + k];
    float lam = *lambd_p;
    float sc  = wscale[cc];
    bool hf   = (cc & 7) != 0;
    int x0    = 4 * tx;
    int z0    = 4 * zc;  // multiple of 4 -> slot = plane & 3

    float win[4][3][6];
    load_plane4<S, 3>(ip, z0 - 1, ty, x0, win);  // (-1)&3 == 3
    load_plane4<S, 0>(ip, z0,     ty, x0, win);
    load_plane4<S, 1>(ip, z0 + 1, ty, x0, win);
    // step z0: prefetch z0+2, compute from (z0-1, z0, z0+1)
    load_plane4<S, 2>(ip, z0 + 2, ty, x0, win);
    conv_compute<S, 3, 0, 1>(z0, ty, x0, wv, win, lam, sc, hf, op);
    // step z0+1: prefetch z0+3 (overwrites z0-1, no longer needed)
    load_plane4<S, 3>(ip, z0 + 3, ty, x0, win);
    conv_compute<S, 0, 1, 2>(z0 + 1, ty, x0, wv, win, lam, sc, hf, op);
    // step z0+2: prefetch z0+4 (zeros when z0=12; overwrites z0)
    load_plane4<S, 0>(ip, z0 + 4, ty, x0, win);
    conv_compute<S, 1, 2, 3>(z0 + 2, ty, x0, wv, win, lam, sc, hf, op);
    // step z0+3
    conv_compute<S, 2, 3, 0>(z0 + 3, ty, x0, wv, win, lam, sc, hf, op);
}

// ========== Final: LDS-tiled base conv + level-1 idwt + level-0 idwt =======
// final_k2 tile/mapping frozen (R1/R4: any tiling or concurrency change
// doubles traffic). R7: epilogue t0/t1 loads HOISTED above the staging loop
// — they are independent of xs, so they issue ~4000 cycles before their use
// instead of after the conv loop (removes the per-block serial load tail).
// VGPR 84 -> ~132, still under the 12-wave LDS-limited budget (<=170).
__global__ __launch_bounds__(256, 3) void final_k2(
    const float* __restrict__ x, const float* __restrict__ t0,
    const float* __restrict__ t1, const float* __restrict__ bw,
    const float* __restrict__ bb, const float* __restrict__ bscale,
    float* __restrict__ out) {
    __shared__ float xs[18 * 10 * 67];
    int bx = blockIdx.x;
    int c  = bx >> 5;
    int ti = bx & 31;
    int dt = ti >> 3;  // z tile (16 thick)
    int ht = ti & 7;   // y tile (8 thick)
    const float* xc = x + ((long)c << 18);

    int tid = threadIdx.x;
    int wc  = tid & 7;         // x chunk: cells w0..w0+3
    int hc  = (tid >> 3) & 3;  // h cell in tile
    int dc  = tid >> 5;        // d cell in tile
    int d   = dt * 8 + dc;
    int h   = ht * 4 + hc;
    int w0  = wc * 4;

    // ---- epilogue data: issue loads FIRST (independent of xs) ----
    int cell0 = (d << 10) + (h << 5) + w0;
    float4 t0v[8];
#pragma unroll
    for (int f = 0; f < 8; ++f)
        t0v[f] = *(const float4*)(t0 + (((long)(c * 8 + f)) << 15) + cell0);
    int s1b = ((d >> 1) * 16 + (h >> 1)) * 16 + (w0 >> 1);
    float2 t1v[8];
#pragma unroll
    for (int f = 0; f < 8; ++f)
        t1v[f] = *(const float2*)(t1 + ((c * 8 + f) << 12) + s1b);

    // ---- stage x tile ----
    int zg0 = 16 * dt - 1, yg0 = 8 * ht - 1;
    for (int i = tid; i < 18 * 10 * 66; i += 256) {
        int pz = i / 660;
        int r  = i - pz * 660;
        int py = r / 66;
        int px = r - py * 66;
        int zg = zg0 + pz, yg = yg0 + py, xg = px - 1;
        bool ok = ((unsigned)zg < 64u) && ((unsigned)yg < 64u) && ((unsigned)xg < 64u);
        xs[(pz * 10 + py) * 67 + px] = ok ? xc[(zg << 12) + (yg << 6) + xg] : 0.f;
    }
    const float* wp0 = bw + c * 27;
    float wv[27];
#pragma unroll
    for (int k = 0; k < 27; ++k) wv[k] = wp0[k];
    float bias = bb[c], scl = bscale[c];
    __syncthreads();

    float acc[2][2][8];
#pragma unroll
    for (int oz = 0; oz < 2; ++oz)
#pragma unroll
        for (int oy = 0; oy < 2; ++oy)
#pragma unroll
            for (int m = 0; m < 8; ++m) acc[oz][oy][m] = 0.f;

#pragma unroll
    for (int pz = 0; pz < 4; ++pz) {
        float r[4][10];
#pragma unroll
        for (int py = 0; py < 4; ++py)
#pragma unroll
            for (int k = 0; k < 10; ++k)
                r[py][k] = xs[((2 * dc + pz) * 10 + (2 * hc + py)) * 67 + 8 * wc + k];
#pragma unroll
        for (int oz = 0; oz < 2; ++oz) {
            int kz = pz - oz;
            if (kz >= 0 && kz <= 2) {
#pragma unroll
                for (int py = 0; py < 4; ++py)
#pragma unroll
                    for (int oy = 0; oy < 2; ++oy) {
                        int ky = py - oy;
                        if (ky >= 0 && ky <= 2) {
#pragma unroll
                            for (int kx = 0; kx < 3; ++kx) {
                                float wgt = wv[kz * 9 + ky * 3 + kx];
#pragma unroll
                                for (int m = 0; m < 8; ++m)
                                    acc[oz][oy][m] += r[py][m + kx] * wgt;
                            }
                        }
                    }
            }
        }
    }

    // epilogue: t0/t1 already in registers; idwt + store
#pragma unroll
    for (int j = 0; j < 4; ++j) {
        int w = w0 + j;
        float tf[8];
#pragma unroll
        for (int f = 0; f < 8; ++f) tf[f] = ((const float*)&t0v[f])[j];
        float add = 0.f;
#pragma unroll
        for (int f = 0; f < 8; ++f) {
            float v  = (j >> 1) ? t1v[f].y : t1v[f].x;
            float sg = 1.f;
            if ((f & 4) && (d & 1)) sg = -sg;
            if ((f & 2) && (h & 1)) sg = -sg;
            if ((f & 1) && (j & 1)) sg = -sg;
            add += sg * v;
        }
        tf[0] += add * SQ3F;
        float contrib[8];
        haar_inv(tf, contrib);
#pragma unroll
        for (int oz = 0; oz < 2; ++oz)
#pragma unroll
            for (int oy = 0; oy < 2; ++oy) {
                float2 rr;
                rr.x = (acc[oz][oy][2 * j] + bias) * scl + contrib[oz * 4 + oy * 2];
                rr.y = (acc[oz][oy][2 * j + 1] + bias) * scl +
                       contrib[oz * 4 + oy * 2 + 1];
                *(float2*)(out + ((long)c << 18) + ((2 * d + oz) << 12) +
                           ((2 * h + oy) << 6) + 2 * w) = rr;
            }
    }
}

extern "C" void kernel_launch(void* const* d_in, const int* in_sizes, int n_in,
                              void* d_out, int out_size, void* d_ws, size_t ws_size,
                              hipStream_t stream) {
    const float* x      = (const float*)d_in[0];
    const float* base_w = (const float*)d_in[1];
    const float* base_b = (const float*)d_in[2];
    const float* base_s = (const float*)d_in[3];
    const float* w0     = (const float*)d_in[4];
    const float* w1     = (const float*)d_in[5];
    const float* ws0    = (const float*)d_in[6];
    const float* ws1    = (const float*)d_in[7];
    const float* lambd  = (const float*)d_in[8];
    float* out = (float*)d_out;

    // Workspace (floats): t0 16.8M | cx1 2.1M | t1 2.1M
    float* t0  = (float*)d_ws;
    float* cx1 = t0 + 16777216;
    float* t1  = cx1 + 2097152;

    // Level 0 fused: x -> t0 (conv+soft+scale, all 8 bands) + level-1 DWT cx1
    fused_l0_k<<<1024, 512, 0, stream>>>(x, w0, ws0, lambd, t0, cx1);
    // Level 1 conv+soft (software-pipelined)
    dwconv_soft_pipe_k<16, 4><<<512, 256, 0, stream>>>(cx1, w1, ws1, lambd, t1);
    // Final: base conv + level-1 idwt (fused) + level-0 idwt
    final_k2<<<2048, 256, 0, stream>>>(x, t0, t1, base_w, base_b, base_s, out);
}